// Round 1
// baseline (12794.067 us; speedup 1.0000x reference)
//
#include <hip/hip_runtime.h>
#include <hip/hip_bf16.h>
#include <stdint.h>
#include <math.h>

#define NB   64      // batch
#define NT   2048    // time steps
#define NF   256     // input features
#define NH   256     // hidden
#define NG   768     // 3*NH

// ================= Kernel 1: xi = x @ Wi  =================
// block: 256 threads, computes 32 rows x 768 cols. Wi streamed from L2
// (768KB/block, 4096 blocks -> ~3GB L2 reads, well under L2 BW).
template<int STORE_BF16>
__global__ __launch_bounds__(256, 2) void xi_gemm(const float* __restrict__ x,
                                                  const float* __restrict__ Wi,
                                                  void* __restrict__ xi_out) {
    __shared__ float xs[32][256];
    const int tid = threadIdx.x;
    const int r0  = blockIdx.x * 32;

    #pragma unroll
    for (int r = 0; r < 32; ++r)
        xs[r][tid] = x[(size_t)(r0 + r) * NF + tid];
    __syncthreads();

    float acc[32][3];
    #pragma unroll
    for (int r = 0; r < 32; ++r) { acc[r][0] = 0.f; acc[r][1] = 0.f; acc[r][2] = 0.f; }

    // 1-deep prefetch of Wi row
    float w0 = Wi[tid], w1 = Wi[tid + 256], w2 = Wi[tid + 512];
    for (int k = 0; k < NF; ++k) {
        const float cw0 = w0, cw1 = w1, cw2 = w2;
        const int kn = (k + 1 < NF) ? (k + 1) : (NF - 1);
        w0 = Wi[(size_t)kn * NG + tid];
        w1 = Wi[(size_t)kn * NG + tid + 256];
        w2 = Wi[(size_t)kn * NG + tid + 512];
        #pragma unroll
        for (int r = 0; r < 32; ++r) {
            const float xv = xs[r][k];   // wave-uniform LDS broadcast
            acc[r][0] = fmaf(xv, cw0, acc[r][0]);
            acc[r][1] = fmaf(xv, cw1, acc[r][1]);
            acc[r][2] = fmaf(xv, cw2, acc[r][2]);
        }
    }

    if constexpr (STORE_BF16) {
        __hip_bfloat16* xo = (__hip_bfloat16*)xi_out;
        #pragma unroll
        for (int r = 0; r < 32; ++r) {
            #pragma unroll
            for (int j = 0; j < 3; ++j)
                xo[(size_t)(r0 + r) * NG + j * 256 + tid] = __float2bfloat16(acc[r][j]);
        }
    } else {
        float* xo = (float*)xi_out;
        #pragma unroll
        for (int r = 0; r < 32; ++r) {
            #pragma unroll
            for (int j = 0; j < 3; ++j)
                xo[(size_t)(r0 + r) * NG + j * 256 + tid] = acc[r][j];
        }
    }
}

// ================= Kernel 2: recurrent scan =================
// 256 blocks: 4 blocks per batch b. Block `blk` of batch b owns hidden
// units [blk*64, blk*64+64) i.e. 192 of the 768 Wh columns; Wh stays in
// VGPRs (64 f32/thread). 768 threads = (4 k-chunks of 64) x (192 cols),
// waves are (kc,g)-uniform so LDS h reads are pure broadcasts.
// Cross-block h exchange: double-buffered global Hbuf + per-batch
// release/acquire counter. All 256 blocks are co-resident (1/CU).

__device__ __forceinline__ float sigm(float v) { return 1.f / (1.f + expf(-v)); }

template<int MODE>   // 0: xi f32 in ws; 1: xi bf16 in ws; 2: on-the-fly (Wi bf16 in LDS)
__global__ __launch_bounds__(768, 3) void gru_rec(
        const float* __restrict__ carry,
        const void*  __restrict__ xi_ptr,   // MODE 0/1: xi buffer ; MODE 2: x
        const float* __restrict__ Wi,       // MODE 2 only
        const float* __restrict__ Wh,
        const float* __restrict__ bh,
        float* __restrict__ out_carry,
        float* __restrict__ out_hidden,
        float* __restrict__ Hbuf,
        int*   __restrict__ flags) {
    __shared__ float hs[NH];
    __shared__ float hp_s[192];
    __shared__ float xi_s[192];
    __shared__ float red[4][192];
    __shared__ float redxi[MODE == 2 ? 4 : 1][MODE == 2 ? 192 : 1];
    __shared__ float xsh[MODE == 2 ? NF : 1];
    __shared__ __hip_bfloat16 wi_l[MODE == 2 ? NF * 192 : 1];

    const int tid = threadIdx.x;
    const int bid = blockIdx.x;
    const int b   = bid & 63;
    const int blk = bid >> 6;
    const int U0  = blk * 64;
    const int kc  = tid / 192;          // 0..3  (k-chunk of 64)
    const int c   = tid - kc * 192;     // 0..191
    const int g   = c >> 6;             // gate 0..2
    const int u   = c & 63;             // unit within our 64
    const int col = g * 256 + U0 + u;   // column of Wh / Wi / bh

    // register-stationary Wh chunk
    float wh[64];
    #pragma unroll
    for (int j = 0; j < 64; ++j)
        wh[j] = Wh[(size_t)(kc * 64 + j) * NG + col];
    const float bias = bh[col];

    if constexpr (MODE == 2) {
        for (int idx = tid; idx < NF * 192; idx += 768) {
            const int k   = idx / 192;
            const int cc  = idx - k * 192;
            const int cl2 = (cc >> 6) * 256 + U0 + (cc & 63);
            wi_l[idx] = __float2bfloat16(Wi[(size_t)k * NG + cl2]);
        }
        if (tid < NF) xsh[tid] = ((const float*)xi_ptr)[(size_t)b * NT * NF + tid];
    }

    if (tid < NH) hs[tid] = carry[(size_t)b * NH + tid];
    __syncthreads();

    float xi_cur = 0.f;
    if constexpr (MODE == 0) {
        if (tid < 192) xi_cur = ((const float*)xi_ptr)[(size_t)b * NT * NG + col];
    } else if constexpr (MODE == 1) {
        if (tid < 192) xi_cur = __bfloat162float(((const __hip_bfloat16*)xi_ptr)[(size_t)b * NT * NG + col]);
    }

    float hlast = 0.f;
    for (int t = 0; t < NT; ++t) {
        // ---- prefetch next step's xi / x row (independent of h -> full overlap)
        float nxt = 0.f;
        if constexpr (MODE == 0) {
            if (tid < 192 && t + 1 < NT)
                nxt = ((const float*)xi_ptr)[((size_t)b * NT + t + 1) * NG + col];
        } else if constexpr (MODE == 1) {
            if (tid < 192 && t + 1 < NT)
                nxt = __bfloat162float(((const __hip_bfloat16*)xi_ptr)[((size_t)b * NT + t + 1) * NG + col]);
        } else {
            if (tid < NF && t + 1 < NT)
                nxt = ((const float*)xi_ptr)[((size_t)b * NT + t + 1) * NF + tid];
        }

        // ---- GEMV partials: hp[col] partial over our k-chunk
        float a0 = 0.f, a1 = 0.f, a2 = 0.f, a3 = 0.f;
        #pragma unroll
        for (int j = 0; j < 64; j += 4) {
            const float4 hv = *(const float4*)&hs[kc * 64 + j];  // uniform -> broadcast
            a0 = fmaf(wh[j + 0], hv.x, a0);
            a1 = fmaf(wh[j + 1], hv.y, a1);
            a2 = fmaf(wh[j + 2], hv.z, a2);
            a3 = fmaf(wh[j + 3], hv.w, a3);
        }
        red[kc][c] = (a0 + a1) + (a2 + a3);

        if constexpr (MODE == 2) {
            float x0 = 0.f, x1 = 0.f, x2 = 0.f, x3 = 0.f;
            #pragma unroll
            for (int j = 0; j < 64; j += 4) {
                const float4 xv = *(const float4*)&xsh[kc * 64 + j];
                x0 = fmaf(__bfloat162float(wi_l[(kc * 64 + j + 0) * 192 + c]), xv.x, x0);
                x1 = fmaf(__bfloat162float(wi_l[(kc * 64 + j + 1) * 192 + c]), xv.y, x1);
                x2 = fmaf(__bfloat162float(wi_l[(kc * 64 + j + 2) * 192 + c]), xv.z, x2);
                x3 = fmaf(__bfloat162float(wi_l[(kc * 64 + j + 3) * 192 + c]), xv.w, x3);
            }
            redxi[kc][c] = (x0 + x1) + (x2 + x3);
        }
        __syncthreads();

        // ---- reduce over k-chunks
        if (tid < 192) {
            hp_s[c] = red[0][c] + red[1][c] + red[2][c] + red[3][c] + bias;
            if constexpr (MODE == 2)
                xi_s[c] = redxi[0][c] + redxi[1][c] + redxi[2][c] + redxi[3][c];
            else
                xi_s[c] = xi_cur;
        }
        __syncthreads();

        // ---- gates (wave 0)
        if (tid < 64) {
            const float r  = sigm(xi_s[tid]       + hp_s[tid]);
            const float z  = sigm(xi_s[64 + tid]  + hp_s[64 + tid]);
            const float n  = tanhf(xi_s[128 + tid] + r * hp_s[128 + tid]);
            const float ho = hs[U0 + tid];
            const float hn = (1.f - z) * n + z * ho;
            out_hidden[((size_t)b * NT + t) * NH + U0 + tid] = hn;
            Hbuf[(size_t)((t + 1) & 1) * NB * NH + (size_t)b * NH + U0 + tid] = hn;
            hlast = hn;
        }

        if (t + 1 < NT) {
            if (tid == 0) {
                // release: orders wave 0's Hbuf stores before the flag bump
                __hip_atomic_fetch_add(&flags[b * 32], 1, __ATOMIC_RELEASE, __HIP_MEMORY_SCOPE_AGENT);
                while (__hip_atomic_load(&flags[b * 32], __ATOMIC_ACQUIRE, __HIP_MEMORY_SCOPE_AGENT) < 4 * (t + 1)) {}
            }
            __syncthreads();
            if (tid < NH)
                hs[tid] = __hip_atomic_load(&Hbuf[(size_t)((t + 1) & 1) * NB * NH + (size_t)b * NH + tid],
                                            __ATOMIC_RELAXED, __HIP_MEMORY_SCOPE_AGENT);
            if constexpr (MODE == 2) { if (tid < NF) xsh[tid] = nxt; }
            else xi_cur = nxt;
            __syncthreads();
        }
    }

    if (tid < 64) out_carry[(size_t)b * NH + U0 + tid] = hlast;
}

// ================= host =================
extern "C" void kernel_launch(void* const* d_in, const int* in_sizes, int n_in,
                              void* d_out, int out_size, void* d_ws, size_t ws_size,
                              hipStream_t stream) {
    const float* carry = (const float*)d_in[0];
    const float* x     = (const float*)d_in[1];
    const float* Wi    = (const float*)d_in[2];
    const float* Wh    = (const float*)d_in[3];
    const float* bh    = (const float*)d_in[4];

    float* out_carry  = (float*)d_out;
    float* out_hidden = out_carry + (size_t)NB * NH;

    const size_t XI_F32 = (size_t)NB * NT * NG * 4;
    const size_t XI_B16 = (size_t)NB * NT * NG * 2;
    const size_t HBUFSZ = (size_t)2 * NB * NH * 4;
    const size_t FLAGSZ = (size_t)NB * 32 * 4;   // 128B stride per batch

    int mode;
    size_t xi_bytes;
    if (ws_size >= XI_F32 + HBUFSZ + FLAGSZ)      { mode = 0; xi_bytes = XI_F32; }
    else if (ws_size >= XI_B16 + HBUFSZ + FLAGSZ) { mode = 1; xi_bytes = XI_B16; }
    else                                          { mode = 2; xi_bytes = 0; }

    char*  wsb   = (char*)d_ws;
    void*  xi    = (void*)wsb;
    float* Hbuf  = (float*)(wsb + xi_bytes);
    int*   flags = (int*)(wsb + xi_bytes + HBUFSZ);

    hipMemsetAsync(flags, 0, FLAGSZ, stream);

    if (mode == 0) {
        xi_gemm<0><<<dim3(NB * NT / 32), dim3(256), 0, stream>>>(x, Wi, xi);
        gru_rec<0><<<dim3(256), dim3(768), 0, stream>>>(carry, xi, nullptr, Wh, bh,
                                                        out_carry, out_hidden, Hbuf, flags);
    } else if (mode == 1) {
        xi_gemm<1><<<dim3(NB * NT / 32), dim3(256), 0, stream>>>(x, Wi, xi);
        gru_rec<1><<<dim3(256), dim3(768), 0, stream>>>(carry, xi, nullptr, Wh, bh,
                                                        out_carry, out_hidden, Hbuf, flags);
    } else {
        gru_rec<2><<<dim3(256), dim3(768), 0, stream>>>(carry, x, Wi, Wh, bh,
                                                        out_carry, out_hidden, Hbuf, flags);
    }
}

// Round 3
// 3067.169 us; speedup vs baseline: 4.1713x; 4.1713x over previous
//
#include <hip/hip_runtime.h>
#include <hip/hip_bf16.h>
#include <stdint.h>
#include <math.h>

#define NB   64      // batch
#define NT   2048    // time steps
#define NF   256     // input features
#define NH   256     // hidden
#define NG   768     // 3*NH

typedef unsigned int u32;
typedef _Float16 f16;
typedef f16 half2v __attribute__((ext_vector_type(2)));

__device__ __forceinline__ u32 packpair(float a, float b) {
    return __builtin_bit_cast(u32, __builtin_amdgcn_cvt_pkrtz(a, b));   // v_cvt_pkrtz_f16_f32
}

__device__ __forceinline__ float fdot2u(u32 w, u32 h, float acc) {
#if __has_builtin(__builtin_amdgcn_fdot2)
    return __builtin_amdgcn_fdot2(__builtin_bit_cast(half2v, w),
                                  __builtin_bit_cast(half2v, h), acc, false);
#else
    half2v wv = __builtin_bit_cast(half2v, w), hv = __builtin_bit_cast(half2v, h);
    return fmaf((float)wv[1], (float)hv[1], fmaf((float)wv[0], (float)hv[0], acc));
#endif
}

// sum over the 4 lanes of each quad (lane^1 then lane^2) — pure-VALU DPP
__device__ __forceinline__ float quad_sum(float v) {
    int i = __builtin_bit_cast(int, v);
    v += __builtin_bit_cast(float, __builtin_amdgcn_update_dpp(0, i, 0xB1, 0xF, 0xF, true)); // quad_perm [1,0,3,2]
    i = __builtin_bit_cast(int, v);
    v += __builtin_bit_cast(float, __builtin_amdgcn_update_dpp(0, i, 0x4E, 0xF, 0xF, true)); // quad_perm [2,3,0,1]
    return v;
}

// ================= Kernel 1: xi = x @ Wi  (f16 output, dot2 inner) =========
// 256 threads, 32 rows x 768 cols per block. x packed to f16 pairs in LDS;
// Wi rows packed on the fly; v_dot2_f32_f16 halves the VALU inst count.
__global__ __launch_bounds__(256, 2) void xi_gemm(const float* __restrict__ x,
                                                  const float* __restrict__ Wi,
                                                  f16* __restrict__ xi) {
    __shared__ u32 xs2[32][128];           // xs2[r][p] = (x[r][2p], x[r][2p+1]) f16
    const int tid = threadIdx.x;
    const int r0  = blockIdx.x * 32;
    {
        const int hi = tid >> 7, lo = tid & 127;
        #pragma unroll
        for (int rr = 0; rr < 16; ++rr) {
            const int r = rr * 2 + hi;
            const float2 v = *(const float2*)&x[(size_t)(r0 + r) * NF + lo * 2];
            xs2[r][lo] = packpair(v.x, v.y);
        }
    }
    __syncthreads();

    float acc[32][3];
    #pragma unroll
    for (int r = 0; r < 32; ++r) { acc[r][0] = 0.f; acc[r][1] = 0.f; acc[r][2] = 0.f; }

    for (int kp2 = 0; kp2 < 64; ++kp2) {   // 4 K-rows per iteration
        const int k = kp2 * 4;
        u32 wA[3], wB[3];
        #pragma unroll
        for (int j = 0; j < 3; ++j) {
            const float* wp = &Wi[(size_t)k * NG + j * 256 + tid];
            wA[j] = packpair(wp[0],              wp[NG]);
            wB[j] = packpair(wp[2 * (size_t)NG], wp[3 * (size_t)NG]);
        }
        #pragma unroll
        for (int r = 0; r < 32; ++r) {
            const uint2 xv = *(const uint2*)&xs2[r][kp2 * 2];   // uniform -> broadcast
            #pragma unroll
            for (int j = 0; j < 3; ++j)
                acc[r][j] = fdot2u(wB[j], xv.y, fdot2u(wA[j], xv.x, acc[r][j]));
        }
    }

    #pragma unroll
    for (int r = 0; r < 32; ++r)
        #pragma unroll
        for (int j = 0; j < 3; ++j)
            xi[(size_t)(r0 + r) * NG + j * 256 + tid] = (f16)acc[r][j];
}

// ================= Kernel 2: recurrent scan — ONE block per batch ==========
// 64 blocks x 768 threads. thread = (c = tid>>2 in [0,192), kc = tid&3).
// Owns cols [4c,4c+4) x k in [64kc, 64kc+64): 128 packed-f16 Wh VGPRs.
// Cross-k reduce = 2 DPP quad adds. h kept in LDS as f16 pairs, replicated
// 4x at shifted offsets so the per-quad ds_read_b128 is conflict-free.
// No cross-block sync at all: 2 __syncthreads per step.
__global__ __launch_bounds__(768) void gru_rec(
        const float* __restrict__ carry,
        const f16*   __restrict__ xi,
        const float* __restrict__ Wh,
        const float* __restrict__ bh,
        float* __restrict__ out_carry,
        float* __restrict__ out_hidden) {
    __shared__ u32   hsh2[4][132];     // 4 bank-shifted replicas of packed h
    __shared__ float hp_lds[NG];
    __shared__ float bsh[NG];

    const int tid  = threadIdx.x;
    const int b    = blockIdx.x;
    const int c    = tid >> 2;         // 0..191
    const int kc   = tid & 3;          // 0..3
    const int col0 = c * 4;
    const int k0   = kc * 64;

    // -------- register-stationary Wh (packed f16 pairs) --------
    u32 wh2[128];                      // wh2[j*32+p] = (Wh[k0+2p][col0+j], Wh[k0+2p+1][col0+j])
    #pragma unroll
    for (int j = 0; j < 4; ++j)
        #pragma unroll
        for (int p = 0; p < 32; ++p) {
            const float* wp = &Wh[(size_t)(k0 + 2 * p) * NG + col0 + j];
            wh2[j * 32 + p] = packpair(wp[0], wp[NG]);
        }

    if (tid < NG) bsh[tid] = bh[tid];
    float hreg = 0.f;
    if (tid < NH) {
        hreg = carry[(size_t)b * NH + tid];
        const f16 hf = (f16)hreg;
        #pragma unroll
        for (int rc = 0; rc < 4; ++rc) ((f16*)&hsh2[rc][0])[tid] = hf;
    }
    __syncthreads();

    const f16* xb = xi + (size_t)b * NT * NG;
    // depth-2 xi prefetch registers (gate threads only use them)
    float x0 = 0.f, x1 = 0.f, x2 = 0.f, y0 = 0.f, y1 = 0.f, y2 = 0.f;
    if (tid < NH) {
        x0 = (float)xb[tid];      x1 = (float)xb[256 + tid];      x2 = (float)xb[512 + tid];
        y0 = (float)xb[NG + tid]; y1 = (float)xb[NG + 256 + tid]; y2 = (float)xb[NG + 512 + tid];
    }

#define GRU_STEP(T, X0, X1, X2)                                                   \
    {                                                                             \
        float n0 = 0.f, n1 = 0.f, n2 = 0.f;                                       \
        if (tid < NH && (T) + 2 < NT) {                                           \
            const f16* xp = xb + (size_t)((T) + 2) * NG + tid;                    \
            n0 = (float)xp[0]; n1 = (float)xp[256]; n2 = (float)xp[512];          \
        }                                                                         \
        float a0 = 0.f, a1 = 0.f, a2 = 0.f, a3 = 0.f;                             \
        const uint4* hp4 = (const uint4*)&hsh2[kc][kc * 32];                      \
        _Pragma("unroll")                                                         \
        for (int p4 = 0; p4 < 8; ++p4) {                                          \
            const uint4 hv = hp4[p4];                                             \
            a0 = fdot2u(wh2[  0 + p4 * 4 + 0], hv.x, a0);                         \
            a1 = fdot2u(wh2[ 32 + p4 * 4 + 0], hv.x, a1);                         \
            a2 = fdot2u(wh2[ 64 + p4 * 4 + 0], hv.x, a2);                         \
            a3 = fdot2u(wh2[ 96 + p4 * 4 + 0], hv.x, a3);                         \
            a0 = fdot2u(wh2[  0 + p4 * 4 + 1], hv.y, a0);                         \
            a1 = fdot2u(wh2[ 32 + p4 * 4 + 1], hv.y, a1);                         \
            a2 = fdot2u(wh2[ 64 + p4 * 4 + 1], hv.y, a2);                         \
            a3 = fdot2u(wh2[ 96 + p4 * 4 + 1], hv.y, a3);                         \
            a0 = fdot2u(wh2[  0 + p4 * 4 + 2], hv.z, a0);                         \
            a1 = fdot2u(wh2[ 32 + p4 * 4 + 2], hv.z, a1);                         \
            a2 = fdot2u(wh2[ 64 + p4 * 4 + 2], hv.z, a2);                         \
            a3 = fdot2u(wh2[ 96 + p4 * 4 + 2], hv.z, a3);                         \
            a0 = fdot2u(wh2[  0 + p4 * 4 + 3], hv.w, a0);                         \
            a1 = fdot2u(wh2[ 32 + p4 * 4 + 3], hv.w, a1);                         \
            a2 = fdot2u(wh2[ 64 + p4 * 4 + 3], hv.w, a2);                         \
            a3 = fdot2u(wh2[ 96 + p4 * 4 + 3], hv.w, a3);                         \
        }                                                                         \
        a0 = quad_sum(a0); a1 = quad_sum(a1); a2 = quad_sum(a2); a3 = quad_sum(a3); \
        if (kc == 0) {                                                            \
            float4 hpv; hpv.x = a0; hpv.y = a1; hpv.z = a2; hpv.w = a3;           \
            *(float4*)&hp_lds[col0] = hpv;                                        \
        }                                                                         \
        __syncthreads();                                                          \
        if (tid < NH) {                                                           \
            const float hpr = hp_lds[tid]       + bsh[tid];                       \
            const float hpz = hp_lds[256 + tid] + bsh[256 + tid];                 \
            const float hpn = hp_lds[512 + tid] + bsh[512 + tid];                 \
            const float rg  = 1.f / (1.f + __expf(-((X0) + hpr)));                \
            const float zg  = 1.f / (1.f + __expf(-((X1) + hpz)));                \
            const float tt  = (X2) + rg * hpn;                                    \
            const float ng  = 1.f - 2.f / (__expf(2.f * tt) + 1.f);               \
            const float hn  = (1.f - zg) * ng + zg * hreg;                        \
            hreg = hn;                                                            \
            out_hidden[((size_t)b * NT + (T)) * NH + tid] = hn;                   \
            const f16 hf = (f16)hn;                                               \
            _Pragma("unroll")                                                     \
            for (int rc = 0; rc < 4; ++rc) ((f16*)&hsh2[rc][0])[tid] = hf;        \
        }                                                                         \
        __syncthreads();                                                          \
        X0 = n0; X1 = n1; X2 = n2;                                                \
    }

    for (int t = 0; t < NT; t += 2) {
        GRU_STEP(t,     x0, x1, x2);
        GRU_STEP(t + 1, y0, y1, y2);
    }
#undef GRU_STEP

    if (tid < NH) out_carry[(size_t)b * NH + tid] = hreg;
}

// ================= host =================
extern "C" void kernel_launch(void* const* d_in, const int* in_sizes, int n_in,
                              void* d_out, int out_size, void* d_ws, size_t ws_size,
                              hipStream_t stream) {
    const float* carry = (const float*)d_in[0];
    const float* x     = (const float*)d_in[1];
    const float* Wi    = (const float*)d_in[2];
    const float* Wh    = (const float*)d_in[3];
    const float* bh    = (const float*)d_in[4];

    float* out_carry  = (float*)d_out;
    float* out_hidden = out_carry + (size_t)NB * NH;

    f16* xi = (f16*)d_ws;   // 64*2048*768*2 B = 201.3 MB (round 1 proved ws fits this)

    xi_gemm<<<dim3(NB * NT / 32), dim3(256), 0, stream>>>(x, Wi, xi);
    gru_rec<<<dim3(NB), dim3(768), 0, stream>>>(carry, xi, Wh, bh,
                                                out_carry, out_hidden);
}